// Round 9
// baseline (687.723 us; speedup 1.0000x reference)
//
#include <hip/hip_runtime.h>
#include <hip/hip_bf16.h>
#include <cstdint>

typedef __bf16 bf16_t;
typedef __attribute__((ext_vector_type(8))) __bf16 bf16x8;
typedef __attribute__((ext_vector_type(4))) __bf16 bf16x4;
typedef __attribute__((ext_vector_type(4))) float f32x4;

#define NEXP 8
#define DK   2048
#define DN   2816
#define DN2  5632
#define NP   8192
#define PPE  1024

// ---------- W1+W3 -> interleaved [E][5632][K]: 16-row groups alternate gate/up ----------
__global__ void k_cvt_w13(const float* __restrict__ W1, const float* __restrict__ W3,
                          bf16_t* __restrict__ dst) {
    const int total4 = NEXP * DN * (DK / 4);
    int stride = gridDim.x * blockDim.x;
    for (int i = blockIdx.x * blockDim.x + threadIdx.x; i < 2 * total4; i += stride) {
        int sel = i >= total4;
        int j   = sel ? i - total4 : i;
        int g   = j >> 9;           // source row (K/4 = 512 vec4 per row)
        int c4  = j & 511;
        int e   = g / DN;
        int n   = g - e * DN;
        long drow = (long)e * DN2 + ((n >> 4) << 5) + (n & 15) + (sel ? 16 : 0);
        float4 v = reinterpret_cast<const float4*>(sel ? W3 : W1)[j];
        bf16x4 o = { (bf16_t)v.x, (bf16_t)v.y, (bf16_t)v.z, (bf16_t)v.w };
        *reinterpret_cast<bf16x4*>(dst + drow * DK + c4 * 4) = o;
    }
}

// ---------- flat fp32 -> bf16 ----------
__global__ void k_cvt(const float* __restrict__ src, bf16_t* __restrict__ dst, int total4) {
    int stride = gridDim.x * blockDim.x;
    for (int i = blockIdx.x * blockDim.x + threadIdx.x; i < total4; i += stride) {
        float4 v = reinterpret_cast<const float4*>(src)[i];
        bf16x4 o = { (bf16_t)v.x, (bf16_t)v.y, (bf16_t)v.z, (bf16_t)v.w };
        reinterpret_cast<bf16x4*>(dst)[i] = o;
    }
}

// ---------- gather x rows by sorted_token_ids, convert to bf16 ----------
__global__ void k_gather(const float* __restrict__ x, const int* __restrict__ ids,
                         bf16_t* __restrict__ xg) {
    int i = blockIdx.x * blockDim.x + threadIdx.x;
    if (i >= NP * (DK / 4)) return;
    int p  = i >> 9;
    int c4 = i & 511;
    int tok = ids[p];
    float4 v = reinterpret_cast<const float4*>(x + (size_t)tok * DK)[c4];
    bf16x4 o = { (bf16_t)v.x, (bf16_t)v.y, (bf16_t)v.z, (bf16_t)v.w };
    *reinterpret_cast<bf16x4*>(xg + (size_t)p * DK + c4 * 4) = o;
}

// ---------- async global->LDS, 16B per lane (wave-uniform LDS base) ----------
__device__ __forceinline__ void gl2lds16(const bf16_t* g, bf16_t* l) {
    __builtin_amdgcn_global_load_lds(
        (__attribute__((address_space(1))) void*)(const_cast<bf16_t*>(g)),
        (__attribute__((address_space(3))) void*)(l), 16, 0, 0);
}

#define BARX()  __builtin_amdgcn_s_barrier()
#define LGKM0() asm volatile("s_waitcnt lgkmcnt(0)" ::: "memory")
#define VMW10() asm volatile("s_waitcnt vmcnt(10)" ::: "memory")
#define VMW0()  asm volatile("s_waitcnt vmcnt(0)" ::: "memory")

// A: stage one 128-row half-tile via global_load_lds (pre-swizzled source)
#define STGA(BUF, HALF, KT) do {                                                \
    gl2lds16(aSrc + (long)((HALF) * 128) * lda + (long)(KT) * 64,               \
             &As[BUF][(HALF) * 128 + w8][0]);                                   \
    gl2lds16(aSrc + (long)((HALF) * 128 + 64) * lda + (long)(KT) * 64,          \
             &As[BUF][(HALF) * 128 + 64 + w8][0]);                              \
} while (0)

#define LOADA(DST, BASE) do { _Pragma("unroll")                                 \
    for (int mi_ = 0; mi_ < 4; ++mi_) {                                         \
        DST[mi_][0] = *reinterpret_cast<const bf16x8*>((BASE) + aoff0 + mi_ * 1024); \
        DST[mi_][1] = *reinterpret_cast<const bf16x8*>((BASE) + aoff1 + mi_ * 1024); \
    } } while (0)

// B fragment group direct from global: 4 x bf16x8 per wave per 16/32-row group.
// Lane l reads row (base + ni*16 + (l&15)), k-offset (l>>4)*8 — lanes l,l+16,
// l+32,l+48 form one contiguous 64B cacheline per row.
#define BLD(DST, ROWOFF, KT) do { _Pragma("unroll")                             \
    for (int ni_ = 0; ni_ < 2; ++ni_) { _Pragma("unroll")                       \
        for (int kk_ = 0; kk_ < 2; ++kk_)                                       \
            DST[ni_][kk_] = *reinterpret_cast<const bf16x8*>(                   \
                bLane + (long)((ROWOFF) + ni_ * 16) * ldb + (long)(KT) * 64 + kk_ * 32); \
    } } while (0)

#define MFMAQ(AF, BF, MIB, NIB) do {                                            \
    __builtin_amdgcn_s_setprio(1);                                              \
    _Pragma("unroll") for (int kk_ = 0; kk_ < 2; ++kk_)                         \
    _Pragma("unroll") for (int mi_ = 0; mi_ < 4; ++mi_)                         \
    _Pragma("unroll") for (int ni_ = 0; ni_ < 2; ++ni_)                         \
        acc[(MIB) + mi_][(NIB) + ni_] = __builtin_amdgcn_mfma_f32_16x16x32_bf16( \
            AF[mi_][kk_], BF[ni_][kk_], acc[(MIB) + mi_][(NIB) + ni_], 0, 0, 0); \
    __builtin_amdgcn_s_setprio(0);                                              \
} while (0)

// ---------- 256x256 8-phase BT GEMM. A via global_load_lds (XOR-swizzled LDS,
// 64KB only); B operands DIRECT from global to registers (no LDS transit) —
// halves the LDS-read pipe load (the measured wall: ~48 b128/wave/iter at 4x/2x
// operand duplication through one 128B/cyc pipe).
// B-reg ping-pong: bl0 (even tiles, issue P5 -> use next P1, 4-phase flight),
// bl1 (odd tiles, issue P1 -> use P5), bhS shared (issue P4/P8 -> use 2 phases
// later; B panels are L2-resident via nt-major so ~200cyc latency suffices).
// A staging: P1:buf1.h1(t+1) P4:buf0.h0(t+2) P5:buf0.h1(t+2) P8:buf1.h0(t+3);
// loop-invariant vmcnt(10) at P4/P8 drains exactly the A-halves read one phase
// later (FIFO-simulated, branchless loop with clamped tile indices).
// EPI=0: fused sigmoid(gate)*up epilogue (interleaved B), writes h bf16 [NP][DN].
// EPI=1: scale by tw[pair], atomicAdd scatter into out fp32 [NTOK][DK].
template <int EPI>
__launch_bounds__(512, 2)
__global__ void k_gemm(const bf16_t* __restrict__ A, const bf16_t* __restrict__ B,
                       bf16_t* __restrict__ Hout, float* __restrict__ Fout,
                       const float* __restrict__ tw, const int* __restrict__ ids,
                       int Mtiles, int Ntiles, int nkt, int lda, int ldb,
                       long aStride, long bStride) {
    __shared__ bf16_t As[2][256][64];     // 64KB, A only

    // XCD-bijective swizzle (grid % 8 == 0), nt-major within expert
    const int nwg = gridDim.x;
    const int logical = (blockIdx.x & 7) * (nwg >> 3) + (blockIdx.x >> 3);
    const int tpe = Mtiles * Ntiles;
    const int e  = logical / tpe;
    const int r  = logical - e * tpe;
    const int nt = r / Mtiles;          // B-panel sharers consecutive -> L2
    const int mt = r - nt * Mtiles;

    const int tid  = threadIdx.x;
    const int w    = tid >> 6;
    const int w8   = w * 8;
    const int lane = tid & 63;
    const int wr = w >> 2, wc = w & 3;        // 2(M) x 4(N) waves, 128x64/wave
    const int fr = lane & 15;
    const int fc = lane >> 4;

    // A staging source: pre-swizzled global chunk (involution c' = c ^ (row&7))
    const int srow = tid >> 3;
    const int schk = (tid & 7) ^ (srow & 7);
    const bf16_t* aSrc = A + (long)e * aStride + ((long)mt * 256 + srow) * lda + schk * 8;

    // B per-lane fragment base (row wc*64+fr, k-offset fc*8)
    const bf16_t* bLane = B + (long)e * bStride
                        + ((long)nt * 256 + wc * 64 + fr) * ldb + fc * 8;

    // A ds_read element offsets (swizzled)
    const int sx = lane & 7;
    const int aoff0 = (wr * 128 + fr) * 64 + ((0 + fc) ^ sx) * 8;
    const int aoff1 = (wr * 128 + fr) * 64 + ((4 + fc) ^ sx) * 8;

    const bf16_t* As0 = &As[0][0][0];
    const bf16_t* As1 = &As[1][0][0];

    f32x4 acc[8][4];
#pragma unroll
    for (int a = 0; a < 8; ++a)
#pragma unroll
        for (int b = 0; b < 4; ++b) acc[a][b] = (f32x4){0.f, 0.f, 0.f, 0.f};

    bf16x8 a[4][2];                  // shared af/ah fragment regs (32 VGPR)
    bf16x8 bl0[2][2], bl1[2][2], bhS[2][2];   // 48 VGPR

    const int last = nkt - 1;

    // ---- prologue: A(0) h0+h1, A(1) h0 staged; bl0/bhS <- B(0) ----
    STGA(0, 0, 0); STGA(0, 1, 0);
    STGA(1, 0, 1);
    BLD(bl0, 0, 0);
    BLD(bhS, 32, 0);
    VMW10();          // drains A(0) x4; leaves A(1).h0 + bl0 + bhS in flight
    BARX();

    const int nIter = nkt >> 1;
    for (int it = 0; it < nIter; ++it) {
        const int t = it * 2;
        const int tc2 = t + 2 < last ? t + 2 : last;
        const int tc3 = t + 3 < last ? t + 3 : last;
        // P1: dsread af(buf0) | stage buf1.h1 <- A(t+1) | issue bl1 <- B(t+1)
        LOADA(a, As0);
        STGA(1, 1, t + 1);
        BLD(bl1, 0, t + 1);
        BARX(); LGKM0();
        MFMAQ(a, bl0, 0, 0);
        BARX();
        // P2: (no loads)
        BARX();
        MFMAQ(a, bhS, 0, 2);
        BARX();
        // P3: dsread ah(buf0)
        LOADA(a, As0 + 4096);
        BARX(); LGKM0();
        MFMAQ(a, bhS, 4, 2);
        BARX();
        // P4: stage buf0.h0 <- A(tc2) | issue bhS <- B(t+1).bh | vmcnt(10)
        STGA(0, 0, tc2);
        BLD(bhS, 32, t + 1);
        VMW10();
        BARX();
        MFMAQ(a, bl0, 4, 0);
        BARX();
        // P5: dsread af(buf1) | stage buf0.h1 <- A(tc2) | issue bl0 <- B(tc2)
        LOADA(a, As1);
        STGA(0, 1, tc2);
        BLD(bl0, 0, tc2);
        BARX(); LGKM0();
        MFMAQ(a, bl1, 0, 0);
        BARX();
        // P6: (no loads)
        BARX();
        MFMAQ(a, bhS, 0, 2);
        BARX();
        // P7: dsread ah(buf1)
        LOADA(a, As1 + 4096);
        BARX(); LGKM0();
        MFMAQ(a, bhS, 4, 2);
        BARX();
        // P8: stage buf1.h0 <- A(tc3) | issue bhS <- B(tc2).bh | vmcnt(10)
        STGA(1, 0, tc3);
        BLD(bhS, 32, tc2);
        VMW10();
        BARX();
        MFMAQ(a, bl1, 4, 0);
        BARX();
    }
    VMW0(); LGKM0();

    if constexpr (EPI == 0) {
        // interleaved cols: ni even = gate, ni odd = up (same real n)
        const long prow0 = (long)e * PPE + (long)mt * 256 + wr * 128 + fc * 4;
        const int col0 = nt * 128 + wc * 32 + fr;
#pragma unroll
        for (int mi = 0; mi < 8; ++mi)
#pragma unroll
            for (int i = 0; i < 4; ++i) {
                long row = prow0 + mi * 16 + i;
#pragma unroll
                for (int p = 0; p < 2; ++p) {
                    float g = acc[mi][2 * p][i];
                    float u = acc[mi][2 * p + 1][i];
                    float s = 1.f / (1.f + __expf(-g));
                    Hout[row * DN + col0 + p * 16] = (bf16_t)(s * u);
                }
            }
    } else {
        const int p0 = e * PPE + mt * 256 + wr * 128 + fc * 4;
        const int col0 = nt * 256 + wc * 64 + fr;
#pragma unroll
        for (int mi = 0; mi < 8; ++mi)
#pragma unroll
            for (int i = 0; i < 4; ++i) {
                int gp = p0 + mi * 16 + i;
                float wgt = tw[gp];
                float* ob = Fout + (long)ids[gp] * DK + col0;
#pragma unroll
                for (int ni = 0; ni < 4; ++ni)
                    atomicAdd(ob + ni * 16, acc[mi][ni][i] * wgt);
            }
    }
}

extern "C" void kernel_launch(void* const* d_in, const int* in_sizes, int n_in,
                              void* d_out, int out_size, void* d_ws, size_t ws_size,
                              hipStream_t stream) {
    const float* x   = (const float*)d_in[0];
    const float* W1  = (const float*)d_in[1];
    const float* W3  = (const float*)d_in[2];
    const float* W2  = (const float*)d_in[3];
    const float* tw  = (const float*)d_in[4];
    const int*   sid = (const int*)d_in[5];
    float* out = (float*)d_out;

    // workspace layout (~340 MB)
    char* ws = (char*)d_ws;
    bf16_t* w13i = (bf16_t*)ws;                      // [E][5632][2048] interleaved, 176MB
    bf16_t* w2b  = (bf16_t*)(ws + 184549376L);       // [E][2048][2816],             88MB
    bf16_t* xg   = (bf16_t*)(ws + 276824064L);       // [8192][2048],                32MB
    bf16_t* h    = (bf16_t*)(ws + 310378496L);       // [8192][2816],                44MB

    hipMemsetAsync(d_out, 0, (size_t)out_size * sizeof(float), stream);

    k_cvt_w13<<<2048, 256, 0, stream>>>(W1, W3, w13i);
    k_cvt<<<2048, 256, 0, stream>>>(W2, w2b, NEXP * DK * (DN / 4));
    k_gather<<<NP * (DK / 4) / 256, 256, 0, stream>>>(x, sid, xg);

    // GEMM1+act: h[p,n] = sigmoid(xg.W1^T) * (xg.W3^T), interleaved weights
    k_gemm<0><<<NEXP * 4 * 22, 512, 0, stream>>>(
        xg, w13i, h, nullptr, nullptr, nullptr,
        4, 22, 32, DK, DK, (long)PPE * DK, (long)DN2 * DK);

    // GEMM2: out[tok,k] += tw[p] * h[p,:] . w2b[e,k,:]^T
    k_gemm<1><<<NEXP * 4 * 8, 512, 0, stream>>>(
        h, w2b, nullptr, out, tw, sid,
        4, 8, 44, DN, DN, (long)PPE * DN, (long)DK * DN);
}

// Round 10
// 549.246 us; speedup vs baseline: 1.2521x; 1.2521x over previous
//
#include <hip/hip_runtime.h>
#include <hip/hip_bf16.h>
#include <cstdint>

typedef __bf16 bf16_t;
typedef __attribute__((ext_vector_type(8))) __bf16 bf16x8;
typedef __attribute__((ext_vector_type(4))) __bf16 bf16x4;
typedef __attribute__((ext_vector_type(4))) float f32x4;

#define NEXP 8
#define DK   2048
#define DN   2816
#define DN2  5632
#define NP   8192
#define PPE  1024

// ---------- W1+W3 -> interleaved [E][5632][K]: 16-row groups alternate gate/up ----------
__global__ void k_cvt_w13(const float* __restrict__ W1, const float* __restrict__ W3,
                          bf16_t* __restrict__ dst) {
    const int total4 = NEXP * DN * (DK / 4);
    int stride = gridDim.x * blockDim.x;
    for (int i = blockIdx.x * blockDim.x + threadIdx.x; i < 2 * total4; i += stride) {
        int sel = i >= total4;
        int j   = sel ? i - total4 : i;
        int g   = j >> 9;           // source row (K/4 = 512 vec4 per row)
        int c4  = j & 511;
        int e   = g / DN;
        int n   = g - e * DN;
        long drow = (long)e * DN2 + ((n >> 4) << 5) + (n & 15) + (sel ? 16 : 0);
        float4 v = reinterpret_cast<const float4*>(sel ? W3 : W1)[j];
        bf16x4 o = { (bf16_t)v.x, (bf16_t)v.y, (bf16_t)v.z, (bf16_t)v.w };
        *reinterpret_cast<bf16x4*>(dst + drow * DK + c4 * 4) = o;
    }
}

// ---------- flat fp32 -> bf16 ----------
__global__ void k_cvt(const float* __restrict__ src, bf16_t* __restrict__ dst, int total4) {
    int stride = gridDim.x * blockDim.x;
    for (int i = blockIdx.x * blockDim.x + threadIdx.x; i < total4; i += stride) {
        float4 v = reinterpret_cast<const float4*>(src)[i];
        bf16x4 o = { (bf16_t)v.x, (bf16_t)v.y, (bf16_t)v.z, (bf16_t)v.w };
        reinterpret_cast<bf16x4*>(dst)[i] = o;
    }
}

// ---------- gather x rows by sorted_token_ids, convert to bf16 ----------
__global__ void k_gather(const float* __restrict__ x, const int* __restrict__ ids,
                         bf16_t* __restrict__ xg) {
    int i = blockIdx.x * blockDim.x + threadIdx.x;
    if (i >= NP * (DK / 4)) return;
    int p  = i >> 9;
    int c4 = i & 511;
    int tok = ids[p];
    float4 v = reinterpret_cast<const float4*>(x + (size_t)tok * DK)[c4];
    bf16x4 o = { (bf16_t)v.x, (bf16_t)v.y, (bf16_t)v.z, (bf16_t)v.w };
    *reinterpret_cast<bf16x4*>(xg + (size_t)p * DK + c4 * 4) = o;
}

// ---------- async global->LDS, 16B per lane (wave-uniform LDS base) ----------
__device__ __forceinline__ void gl2lds16(const bf16_t* g, bf16_t* l) {
    __builtin_amdgcn_global_load_lds(
        (__attribute__((address_space(1))) void*)(const_cast<bf16_t*>(g)),
        (__attribute__((address_space(3))) void*)(l), 16, 0, 0);
}

#define BARX() __builtin_amdgcn_s_barrier()
#define LGKM0() asm volatile("s_waitcnt lgkmcnt(0)" ::: "memory")
#define VMW0() asm volatile("s_waitcnt vmcnt(0)" ::: "memory")

// stage one 128-row half-tile (2 x global_load_lds per thread, 16B each)
#define STG(ARR, SRC, LD, BUF, HALF, KT) do {                                   \
    gl2lds16((SRC) + (long)((HALF) * 128) * (LD) + (long)(KT) * 64,             \
             &ARR[BUF][(HALF) * 128 + w8][0]);                                  \
    gl2lds16((SRC) + (long)((HALF) * 128 + 64) * (LD) + (long)(KT) * 64,        \
             &ARR[BUF][(HALF) * 128 + 64 + w8][0]);                             \
} while (0)
// stage a full 256-row buffer (A or B), 4 loads/thread
#define STGF(ARR, SRC, LD, BUF, KT) do {                                        \
    STG(ARR, SRC, LD, BUF, 0, KT); STG(ARR, SRC, LD, BUF, 1, KT);               \
} while (0)

#define LOADA(DST, BASE) do { _Pragma("unroll")                                 \
    for (int mi_ = 0; mi_ < 4; ++mi_) {                                         \
        DST[mi_][0] = *reinterpret_cast<const bf16x8*>((BASE) + aoff0 + mi_ * 1024); \
        DST[mi_][1] = *reinterpret_cast<const bf16x8*>((BASE) + aoff1 + mi_ * 1024); \
    } } while (0)

#define LOADB(DST, BASE) do { _Pragma("unroll")                                 \
    for (int ni_ = 0; ni_ < 2; ++ni_) {                                         \
        DST[ni_][0] = *reinterpret_cast<const bf16x8*>((BASE) + boff0 + ni_ * 1024); \
        DST[ni_][1] = *reinterpret_cast<const bf16x8*>((BASE) + boff1 + ni_ * 1024); \
    } } while (0)

#define MFMAQ(AF, BF, MIB, NIB) do {                                            \
    __builtin_amdgcn_s_setprio(1);                                              \
    _Pragma("unroll") for (int kk_ = 0; kk_ < 2; ++kk_)                         \
    _Pragma("unroll") for (int mi_ = 0; mi_ < 4; ++mi_)                         \
    _Pragma("unroll") for (int ni_ = 0; ni_ < 2; ++ni_)                         \
        acc[(MIB) + mi_][(NIB) + ni_] = __builtin_amdgcn_mfma_f32_16x16x32_bf16( \
            AF[mi_][kk_], BF[ni_][kk_], acc[(MIB) + mi_][(NIB) + ni_], 0, 0, 0); \
    __builtin_amdgcn_s_setprio(0);                                              \
} while (0)

// ---------- 256x256 8-phase BT GEMM with ONE-PHASE READ-AHEAD ----------
// Quadrant order per K-tile: Q1(af,bl) Q2(af,bh) Q4(ah,bl) Q3(ah,bh).
// Every ds_read issues one full phase before its MFMA (compiler emits the
// counted lgkm waits from dataflow); frag buffers die exactly when their
// successor's read issues -> no ping-pong registers.
// Fences (only what the compiler can't derive): VMW0+BARX at phase3/7 ends:
//   - WAR: all buf reads complete before the stage (via Q4's data wait + barrier)
//   - RAW: staged batch (8 gl2lds, 3-phase flight ~1300cyc) drained before read.
// Exactly one 8-load batch in flight at each fence. Branchless tail (clamped
// k-tile re-stage into WAR-free regions; final dead reads drained in epilogue).
// EPI=0: fused sigmoid(gate)*up epilogue (interleaved B), writes h bf16 [NP][DN].
// EPI=1: scale by tw[pair], atomicAdd scatter into out fp32 [NTOK][DK].
template <int EPI>
__launch_bounds__(512, 2)
__global__ void k_gemm(const bf16_t* __restrict__ A, const bf16_t* __restrict__ B,
                       bf16_t* __restrict__ Hout, float* __restrict__ Fout,
                       const float* __restrict__ tw, const int* __restrict__ ids,
                       int Mtiles, int Ntiles, int nkt, int lda, int ldb,
                       long aStride, long bStride) {
    __shared__ bf16_t As[2][256][64];
    __shared__ bf16_t Bs[2][256][64];

    // XCD-bijective swizzle (grid % 8 == 0); mt-major (R2 measured-best)
    const int nwg = gridDim.x;
    const int logical = (blockIdx.x & 7) * (nwg >> 3) + (blockIdx.x >> 3);
    const int tpe = Mtiles * Ntiles;
    const int e  = logical / tpe;
    const int r  = logical - e * tpe;
    const int mt = r / Ntiles;
    const int nt = r - mt * Ntiles;

    const int tid  = threadIdx.x;
    const int w    = tid >> 6;
    const int w8   = w * 8;
    const int lane = tid & 63;
    const int wr = w >> 2, wc = w & 3;        // 2(M) x 4(N) wave grid, 128x64/wave
    const int fr = lane & 15;
    const int fc = lane >> 4;

    // staging source: pre-swizzled global chunk (involution: c' = c ^ (row&7))
    const int srow = tid >> 3;                 // 0..63
    const int schk = (tid & 7) ^ (srow & 7);
    const bf16_t* aSrc = A + (long)e * aStride + ((long)mt * 256 + srow) * lda + schk * 8;
    const bf16_t* bSrc = B + (long)e * bStride + ((long)nt * 256 + srow) * ldb + schk * 8;

    // ds_read element offsets (swizzled): row*64 + (chunk ^ (row&7))*8
    const int sx = lane & 7;
    const int aoff0 = (wr * 128 + fr) * 64 + ((0 + fc) ^ sx) * 8;  // kk=0
    const int aoff1 = (wr * 128 + fr) * 64 + ((4 + fc) ^ sx) * 8;  // kk=1
    const int boff0 = (wc * 64 + fr) * 64 + ((0 + fc) ^ sx) * 8;
    const int boff1 = (wc * 64 + fr) * 64 + ((4 + fc) ^ sx) * 8;

    const bf16_t* As0 = &As[0][0][0];
    const bf16_t* As1 = &As[1][0][0];
    const bf16_t* Bs0 = &Bs[0][0][0];
    const bf16_t* Bs1 = &Bs[1][0][0];

    f32x4 acc[8][4];
#pragma unroll
    for (int a = 0; a < 8; ++a)
#pragma unroll
        for (int b = 0; b < 4; ++b) acc[a][b] = (f32x4){0.f, 0.f, 0.f, 0.f};

    bf16x8 af[4][2], ah[4][2], bl[2][2], bh[2][2];

    const int last = nkt - 1;

    // prologue: tile0 -> buf0, tile1 -> buf1; drain; pre-read Q1(b0) frags
    STGF(As, aSrc, lda, 0, 0); STGF(Bs, bSrc, ldb, 0, 0);
    STGF(As, aSrc, lda, 1, 1); STGF(Bs, bSrc, ldb, 1, 1);
    VMW0();
    BARX();
    LOADA(af, As0); LOADB(bl, Bs0);

    const int nIter = nkt >> 1;
    for (int it = 0; it < nIter; ++it) {
        const int t = it * 2;
        const int tc2 = t + 2 < last ? t + 2 : last;
        const int tc3 = t + 3 < last ? t + 3 : last;
        // ---- K-tile t (buf0) ----
        // F1: read bh(b0) | Q1
        LOADB(bh, Bs0 + 2048);
        BARX();
        MFMAQ(af, bl, 0, 0);
        // F2: read ah(b0) | Q2
        LOADA(ah, As0 + 4096);
        BARX();
        MFMAQ(af, bh, 0, 2);
        // F3: Q4 | fence: all buf0 reads done (Q4's wait) -> VMW0 (drains
        //     buf1(t+1) batch staged last iter) -> barrier
        BARX();
        MFMAQ(ah, bl, 4, 0);
        VMW0();
        BARX();
        // F4: read Q1(b1) frags | stage buf0 <- tc2 | Q3
        LOADA(af, As1); LOADB(bl, Bs1);
        STGF(Bs, bSrc, ldb, 0, tc2); STGF(As, aSrc, lda, 0, tc2);
        BARX();
        MFMAQ(ah, bh, 4, 2);
        // ---- K-tile t+1 (buf1) ----
        // F5: read bh(b1) | Q1
        LOADB(bh, Bs1 + 2048);
        BARX();
        MFMAQ(af, bl, 0, 0);
        // F6: read ah(b1) | Q2
        LOADA(ah, As1 + 4096);
        BARX();
        MFMAQ(af, bh, 0, 2);
        // F7: Q4 | fence for buf0(tc2) batch
        BARX();
        MFMAQ(ah, bl, 4, 0);
        VMW0();
        BARX();
        // F8: read Q1(b0,next) frags | stage buf1 <- tc3 | Q3
        LOADA(af, As0); LOADB(bl, Bs0);
        STGF(Bs, bSrc, ldb, 1, tc3); STGF(As, aSrc, lda, 1, tc3);
        BARX();
        MFMAQ(ah, bh, 4, 2);
    }
    VMW0(); LGKM0();   // drain final dead reads/stages

    if constexpr (EPI == 0) {
        // interleaved cols: ni even = gate, ni odd = up (same real n)
        const long prow0 = (long)e * PPE + (long)mt * 256 + wr * 128 + fc * 4;
        const int col0 = nt * 128 + wc * 32 + fr;
#pragma unroll
        for (int mi = 0; mi < 8; ++mi)
#pragma unroll
            for (int i = 0; i < 4; ++i) {
                long row = prow0 + mi * 16 + i;
#pragma unroll
                for (int p = 0; p < 2; ++p) {
                    float g = acc[mi][2 * p][i];
                    float u = acc[mi][2 * p + 1][i];
                    float s = 1.f / (1.f + __expf(-g));
                    Hout[row * DN + col0 + p * 16] = (bf16_t)(s * u);
                }
            }
    } else {
        const int p0 = e * PPE + mt * 256 + wr * 128 + fc * 4;
        const int col0 = nt * 256 + wc * 64 + fr;
#pragma unroll
        for (int mi = 0; mi < 8; ++mi)
#pragma unroll
            for (int i = 0; i < 4; ++i) {
                int gp = p0 + mi * 16 + i;
                float wgt = tw[gp];
                float* ob = Fout + (long)ids[gp] * DK + col0;
#pragma unroll
                for (int ni = 0; ni < 4; ++ni)
                    atomicAdd(ob + ni * 16, acc[mi][ni][i] * wgt);
            }
    }
}

extern "C" void kernel_launch(void* const* d_in, const int* in_sizes, int n_in,
                              void* d_out, int out_size, void* d_ws, size_t ws_size,
                              hipStream_t stream) {
    const float* x   = (const float*)d_in[0];
    const float* W1  = (const float*)d_in[1];
    const float* W3  = (const float*)d_in[2];
    const float* W2  = (const float*)d_in[3];
    const float* tw  = (const float*)d_in[4];
    const int*   sid = (const int*)d_in[5];
    float* out = (float*)d_out;

    // workspace layout (~340 MB)
    char* ws = (char*)d_ws;
    bf16_t* w13i = (bf16_t*)ws;                      // [E][5632][2048] interleaved, 176MB
    bf16_t* w2b  = (bf16_t*)(ws + 184549376L);       // [E][2048][2816],             88MB
    bf16_t* xg   = (bf16_t*)(ws + 276824064L);       // [8192][2048],                32MB
    bf16_t* h    = (bf16_t*)(ws + 310378496L);       // [8192][2816],                44MB

    hipMemsetAsync(d_out, 0, (size_t)out_size * sizeof(float), stream);

    k_cvt_w13<<<2048, 256, 0, stream>>>(W1, W3, w13i);
    k_cvt<<<2048, 256, 0, stream>>>(W2, w2b, NEXP * DK * (DN / 4));
    k_gather<<<NP * (DK / 4) / 256, 256, 0, stream>>>(x, sid, xg);

    // GEMM1+act: h[p,n] = sigmoid(xg.W1^T) * (xg.W3^T), interleaved weights
    k_gemm<0><<<NEXP * 4 * 22, 512, 0, stream>>>(
        xg, w13i, h, nullptr, nullptr, nullptr,
        4, 22, 32, DK, DK, (long)PPE * DK, (long)DN2 * DK);

    // GEMM2: out[tok,k] += tw[p] * h[p,:] . w2b[e,k,:]^T
    k_gemm<1><<<NEXP * 4 * 8, 512, 0, stream>>>(
        h, w2b, nullptr, out, tw, sid,
        4, 8, 44, DN, DN, (long)PPE * DN, (long)DK * DN);
}